// Round 11
// baseline (177.850 us; speedup 1.0000x reference)
//
#include <hip/hip_runtime.h>
#include <hip/hip_fp16.h>
#include <math.h>

#define T_TOKENS 16384
#define D_DIM    2048
#define NEXP     256
#define TOPK     8
#define NLIM     4
#define BM       32
#define BK       32
#define KSTEPS   (D_DIM / BK)   // 64
#define NTHREADS 512

typedef __attribute__((ext_vector_type(8))) _Float16 f16x8;  // 4 VGPRs
typedef __attribute__((ext_vector_type(4))) float f32x4;     // MFMA acc

// ---- pre-pass: w[256][2048] f32 -> fp16 in MFMA-fragment order ----
// wf layout (fp16 elems): [ks(64)][nfg(16)][lane(64)][j(8)]
// value = (half) w[ e = nfg*16 + (lane&15) ][ k = ks*32 + (lane>>4)*8 + j ]
__global__ __launch_bounds__(256) void prep_w(const float* __restrict__ w,
                                              unsigned short* __restrict__ wf) {
  const int g   = blockIdx.x * 256 + threadIdx.x;  // 0..65535
  const int ks  = g >> 10;
  const int rem = g & 1023;
  const int nfg = rem >> 6;
  const int l   = rem & 63;
  const int e   = nfg * 16 + (l & 15);
  const int kb  = ks * 32 + ((l >> 4) << 3);
  const float* src = &w[(size_t)e * D_DIM + kb];
  float f[8];
  *reinterpret_cast<float4*>(&f[0]) = *reinterpret_cast<const float4*>(src);
  *reinterpret_cast<float4*>(&f[4]) = *reinterpret_cast<const float4*>(src + 4);
  union { unsigned short s[8]; float4 v; } h;
  #pragma unroll
  for (int j = 0; j < 8; ++j) h.s[j] = __half_as_ushort(__float2half(f[j]));
  *reinterpret_cast<float4*>(wf + (size_t)ks * 8192 + nfg * 512 + l * 8) = h.v;
}

struct AFrag { float4 lo, hi; };   // 8 raw f32 of one A fragment

__device__ __forceinline__ unsigned cvt2(float a, float b) {
  return (unsigned)__half_as_ushort(__float2half(a)) |
         ((unsigned)__half_as_ushort(__float2half(b)) << 16);
}
__device__ __forceinline__ f16x8 cvt8(const AFrag& r) {
  union { unsigned u[4]; f16x8 v; } h;
  h.u[0] = cvt2(r.lo.x, r.lo.y);
  h.u[1] = cvt2(r.lo.z, r.lo.w);
  h.u[2] = cvt2(r.hi.x, r.hi.y);
  h.u[3] = cvt2(r.hi.z, r.hi.w);
  return h.v;
}

// ---- one K-step: issue step t+1 loads into (nA,nB); compute step t ----
// All deps are REGISTER deps: the compiler emits its own counted vmcnt waits
// and can software-pipeline freely. No LDS, no barriers in the K-loop.
__device__ __forceinline__ void kstep(
    int t, const float* xp0, const float* xp1, const unsigned short* wfB,
    AFrag (&cA)[2], f16x8 (&cB)[2],
    AFrag (&nA)[2], f16x8 (&nB)[2],
    f32x4 (&acc)[2][2]) {
  const int kn = (t + 1 < KSTEPS) ? t + 1 : KSTEPS - 1;
  // issue next-step loads (earliest possible; may hoist, must not sink)
  nA[0].lo = *reinterpret_cast<const float4*>(xp0 + kn * 32);
  nA[0].hi = *reinterpret_cast<const float4*>(xp0 + kn * 32 + 4);
  nA[1].lo = *reinterpret_cast<const float4*>(xp1 + kn * 32);
  nA[1].hi = *reinterpret_cast<const float4*>(xp1 + kn * 32 + 4);
  nB[0] = *reinterpret_cast<const f16x8*>(wfB + (size_t)kn * 8192);
  nB[1] = *reinterpret_cast<const f16x8*>(wfB + (size_t)kn * 8192 + 512);
  __builtin_amdgcn_sched_barrier(0);
  // compute step t (cur regs loaded one full step ago)
  f16x8 a0 = cvt8(cA[0]);
  f16x8 a1 = cvt8(cA[1]);
  acc[0][0] = __builtin_amdgcn_mfma_f32_16x16x32_f16(a0, cB[0], acc[0][0], 0, 0, 0);
  acc[1][0] = __builtin_amdgcn_mfma_f32_16x16x32_f16(a1, cB[0], acc[1][0], 0, 0, 0);
  acc[0][1] = __builtin_amdgcn_mfma_f32_16x16x32_f16(a0, cB[1], acc[0][1], 0, 0, 0);
  acc[1][1] = __builtin_amdgcn_mfma_f32_16x16x32_f16(a1, cB[1], acc[1][1], 0, 0, 0);
}

// ---- fused GEMM (fp16 MFMA, fully register-resident, barrier-free K-loop)
__global__ __launch_bounds__(NTHREADS, 4) void gate_kernel(
    const float* __restrict__ x,
    const unsigned short* __restrict__ wf,
    const float* __restrict__ bias,
    float* __restrict__ out_w,
    float* __restrict__ out_idx,
    float* __restrict__ out_load) {

  __shared__ float Sc[BM][260];   // +4 pad: breaks row-stride bank alias
  __shared__ int hist[NEXP];

  const int tid  = threadIdx.x;
  const int row0 = blockIdx.x * BM;
  const int lane = tid & 63;
  const int wid  = tid >> 6;   // 0..7 ; wave owns experts wid*32..wid*32+31

  for (int i = tid; i < NEXP; i += NTHREADS) hist[i] = 0;

  // per-lane A sources: frag mf: row = row0 + mf*16 + (lane&15),
  //                     k-base = (lane>>4)*8, step stride 32 floats
  const float* xp0 =
      &x[(size_t)(row0 + (lane & 15)) * D_DIM + ((lane >> 4) << 3)];
  const float* xp1 = xp0 + (size_t)16 * D_DIM;
  // per-lane B source (fragment-linear wf): frag nf at +nf*512, step +8192
  const unsigned short* wfB = wf + (size_t)(wid * 2) * 512 + (size_t)lane * 8;

  f32x4 acc[2][2];
  #pragma unroll
  for (int i = 0; i < 2; ++i)
    #pragma unroll
    for (int j = 0; j < 2; ++j) acc[i][j] = (f32x4)(0.0f);

  AFrag aA[2], aB[2];
  f16x8 bA[2], bB[2];

  // prologue: load step 0
  aA[0].lo = *reinterpret_cast<const float4*>(xp0);
  aA[0].hi = *reinterpret_cast<const float4*>(xp0 + 4);
  aA[1].lo = *reinterpret_cast<const float4*>(xp1);
  aA[1].hi = *reinterpret_cast<const float4*>(xp1 + 4);
  bA[0] = *reinterpret_cast<const f16x8*>(wfB);
  bA[1] = *reinterpret_cast<const f16x8*>(wfB + 512);

  for (int t = 0; t < KSTEPS; t += 2) {
    kstep(t,     xp0, xp1, wfB, aA, bA, aB, bB, acc);
    kstep(t + 1, xp0, xp1, wfB, aB, bB, aA, bA, acc);
  }

  // ---- epilogue: logits -> Sc (C/D layout: col=lane&15, row=(lane>>4)*4+r)
  #pragma unroll
  for (int mf = 0; mf < 2; ++mf)
    #pragma unroll
    for (int nf = 0; nf < 2; ++nf)
      #pragma unroll
      for (int r = 0; r < 4; ++r) {
        const int row = mf * 16 + ((lane >> 4) << 2) + r;
        const int col = wid * 32 + nf * 16 + (lane & 15);
        Sc[row][col] = acc[mf][nf][r];
      }
  __syncthreads();

  // ---- routing: one wave per token, lane holds experts 4l..4l+3
  const float4 bsl = *reinterpret_cast<const float4*>(&bias[lane * 4]);
  const int g = lane >> 3;   // group of this lane's experts

  for (int m = wid; m < BM; m += 8) {
    float v[4];
    *reinterpret_cast<float4*>(v) =
        *reinterpret_cast<const float4*>(&Sc[m][lane * 4]);

    // softmax (match jax: subtract row max, exp, divide by sum)
    float mx = fmaxf(fmaxf(v[0], v[1]), fmaxf(v[2], v[3]));
    #pragma unroll
    for (int s = 1; s < 64; s <<= 1) mx = fmaxf(mx, __shfl_xor(mx, s));
    float ex[4], sum = 0.f;
    #pragma unroll
    for (int j = 0; j < 4; ++j) { ex[j] = expf(v[j] - mx); sum += ex[j]; }
    #pragma unroll
    for (int s = 1; s < 64; s <<= 1) sum += __shfl_xor(sum, s);
    float sc[4], sel[4];
    sc[0] = ex[0] / sum; sc[1] = ex[1] / sum;
    sc[2] = ex[2] / sum; sc[3] = ex[3] / sum;
    sel[0] = sc[0] + bsl.x; sel[1] = sc[1] + bsl.y;
    sel[2] = sc[2] + bsl.z; sel[3] = sc[3] + bsl.w;

    // keep original scores for the gather
    *reinterpret_cast<float4*>(&Sc[m][lane * 4]) =
        make_float4(sc[0], sc[1], sc[2], sc[3]);

    // group max (groups of 32 experts = 8 lanes)
    float gv = fmaxf(fmaxf(sel[0], sel[1]), fmaxf(sel[2], sel[3]));
    gv = fmaxf(gv, __shfl_xor(gv, 1));
    gv = fmaxf(gv, __shfl_xor(gv, 2));
    gv = fmaxf(gv, __shfl_xor(gv, 4));

    // top-4 groups, tie -> lower group index (jax.lax.top_k stability)
    unsigned gmask = 0;
    float gcur = gv;
    #pragma unroll
    for (int it = 0; it < NLIM; ++it) {
      float bv2 = gcur; int bi = g;
      #pragma unroll
      for (int s = 1; s < 64; s <<= 1) {
        float ov = __shfl_xor(bv2, s);
        int   oi = __shfl_xor(bi, s);
        if (ov > bv2 || (ov == bv2 && oi < bi)) { bv2 = ov; bi = oi; }
      }
      gmask |= 1u << bi;
      if (g == bi) gcur = -INFINITY;
    }
    if (!((gmask >> g) & 1u)) {
      sel[0] = sel[1] = sel[2] = sel[3] = -INFINITY;
    }

    // top-8 experts, tie -> lower expert index
    const int gtok = row0 + m;
    #pragma unroll
    for (int it = 0; it < TOPK; ++it) {
      float bv2 = sel[0]; int bi = lane * 4;
      #pragma unroll
      for (int j = 1; j < 4; ++j)
        if (sel[j] > bv2) { bv2 = sel[j]; bi = lane * 4 + j; }
      #pragma unroll
      for (int s = 1; s < 64; s <<= 1) {
        float ov = __shfl_xor(bv2, s);
        int   oi = __shfl_xor(bi, s);
        if (ov > bv2 || (ov == bv2 && oi < bi)) { bv2 = ov; bi = oi; }
      }
      if (lane == 0) {
        out_w[(size_t)gtok * TOPK + it]   = Sc[m][bi] * 2.5f;
        out_idx[(size_t)gtok * TOPK + it] = (float)bi;
        atomicAdd(&hist[bi], 1);
      }
      if ((bi >> 2) == lane) sel[bi & 3] = -INFINITY;
    }
  }

  __syncthreads();
  for (int b = tid; b < NEXP; b += NTHREADS)
    if (hist[b]) atomicAdd(&out_load[b], (float)hist[b]);
}

extern "C" void kernel_launch(void* const* d_in, const int* in_sizes, int n_in,
                              void* d_out, int out_size, void* d_ws, size_t ws_size,
                              hipStream_t stream) {
  const float* x    = (const float*)d_in[0];
  const float* w    = (const float*)d_in[1];
  const float* bias = (const float*)d_in[2];
  float* out_w    = (float*)d_out;
  float* out_idx  = out_w + (size_t)T_TOKENS * TOPK;
  float* out_load = out_idx + (size_t)T_TOKENS * TOPK;
  unsigned short* wfrag = (unsigned short*)d_ws;   // 1 MB fragment-ordered fp16 w

  hipMemsetAsync(out_load, 0, NEXP * sizeof(float), stream);
  prep_w<<<256, 256, 0, stream>>>(w, wfrag);
  gate_kernel<<<T_TOKENS / BM, NTHREADS, 0, stream>>>(
      x, wfrag, bias, out_w, out_idx, out_load);
}

// Round 12
// 125.642 us; speedup vs baseline: 1.4155x; 1.4155x over previous
//
#include <hip/hip_runtime.h>
#include <hip/hip_fp16.h>
#include <math.h>

#define T_TOKENS 16384
#define D_DIM    2048
#define NEXP     256
#define TOPK     8
#define NLIM     4
#define BM       32
#define NSS      16          // supersteps, BK=128 each (4 sub-k of 32)
#define NTHREADS 512

typedef __attribute__((ext_vector_type(8))) _Float16 f16x8;  // 4 VGPRs
typedef __attribute__((ext_vector_type(4))) float f32x4;     // MFMA acc

typedef __attribute__((address_space(1))) const float g_float;
typedef __attribute__((address_space(3))) float l_float;

// LDS: A = raw f32 x-fragments, 3-ring (8 KB/ring); Sc aliases after GEMM.
//  A[ring][ks(4)][mf(2)][jh(2)][lane(64)][4 f32]
struct GemmBufs { float A[3][4][2][2][64][4]; };   // 24 KB
union SMem {
  GemmBufs g;
  float Sc[BM][260];                               // 33.3 KB
};

// ---- pre-pass: w[256][2048] f32 -> fp16 in MFMA-fragment order ----
// wf layout (fp16): [ks(64)][nfg(16)][lane(64)][j(8)]
// value = (half) w[ e = nfg*16 + (lane&15) ][ k = ks*32 + (lane>>4)*8 + j ]
__global__ __launch_bounds__(256) void prep_w(const float* __restrict__ w,
                                              unsigned short* __restrict__ wf) {
  const int g   = blockIdx.x * 256 + threadIdx.x;  // 0..65535
  const int ks  = g >> 10;
  const int rem = g & 1023;
  const int nfg = rem >> 6;
  const int l   = rem & 63;
  const int e   = nfg * 16 + (l & 15);
  const int kb  = ks * 32 + ((l >> 4) << 3);
  const float* src = &w[(size_t)e * D_DIM + kb];
  float f[8];
  *reinterpret_cast<float4*>(&f[0]) = *reinterpret_cast<const float4*>(src);
  *reinterpret_cast<float4*>(&f[4]) = *reinterpret_cast<const float4*>(src + 4);
  union { unsigned short s[8]; float4 v; } h;
  #pragma unroll
  for (int j = 0; j < 8; ++j) h.s[j] = __half_as_ushort(__float2half(f[j]));
  *reinterpret_cast<float4*>(wf + (size_t)ks * 8192 + nfg * 512 + l * 8) = h.v;
}

__device__ __forceinline__ unsigned cvt2(float a, float b) {  // RNE, as r9
  return (unsigned)__half_as_ushort(__float2half(a)) |
         ((unsigned)__half_as_ushort(__float2half(b)) << 16);
}
__device__ __forceinline__ f16x8 cvt8(const float4& lo, const float4& hi) {
  union { unsigned u[4]; f16x8 v; } h;
  h.u[0] = cvt2(lo.x, lo.y); h.u[1] = cvt2(lo.z, lo.w);
  h.u[2] = cvt2(hi.x, hi.y); h.u[3] = cvt2(hi.z, hi.w);
  return h.v;
}

// ---- fused GEMM (fp16 MFMA; A via 3-ring gll-LDS; B in registers) ----
__global__ __launch_bounds__(NTHREADS, 4) void gate_kernel(
    const float* __restrict__ x,
    const unsigned short* __restrict__ wf,
    const float* __restrict__ bias,
    float* __restrict__ out_w,
    float* __restrict__ out_idx,
    float* __restrict__ out_load) {

  __shared__ SMem sm;
  __shared__ int hist[NEXP];

  const int tid  = threadIdx.x;
  const int row0 = blockIdx.x * BM;
  const int lane = tid & 63;
  const int wid  = tid >> 6;   // 0..7 ; wave owns experts wid*32..wid*32+31

  for (int i = tid; i < NEXP; i += NTHREADS) hist[i] = 0;

  // gll lane-source base for A: row = row0 + (lane&15) (+16 for mf=1),
  // k-base = (lane>>4)*8 (+4 for jh=1)
  const float* xsrc = &x[(size_t)(row0 + (lane & 15)) * D_DIM + ((lane >> 4) << 3)];
  // this wave's two chunks: c = 2*wid + i -> (ks=c>>2, mf=(c>>1)&1, jh=c&1)
  const int c0 = wid * 2, c1 = wid * 2 + 1;
  const int ks0 = c0 >> 2, mf0 = (c0 >> 1) & 1, jh0 = c0 & 1;
  const int ks1 = c1 >> 2, mf1 = (c1 >> 1) & 1, jh1 = c1 & 1;
  const float* s0 = xsrc + (size_t)mf0 * 16 * D_DIM + ks0 * 32 + jh0 * 4;
  const float* s1 = xsrc + (size_t)mf1 * 16 * D_DIM + ks1 * 32 + jh1 * 4;
  // B source base (fragment-linear wf)
  const unsigned short* wfB = wf + (size_t)(wid * 2) * 512 + (size_t)lane * 8;

  f32x4 acc[2][2];
  #pragma unroll
  for (int i = 0; i < 2; ++i)
    #pragma unroll
    for (int j = 0; j < 2; ++j) acc[i][j] = (f32x4)(0.0f);

  // ---- prologue: stage supersteps 0 and 1 into rings 0,1
  #pragma unroll
  for (int n = 0; n < 2; ++n) {
    __builtin_amdgcn_global_load_lds((g_float*)(s0 + n * 128),
        (l_float*)&sm.g.A[n][ks0][mf0][jh0][0][0], 16, 0, 0);
    __builtin_amdgcn_global_load_lds((g_float*)(s1 + n * 128),
        (l_float*)&sm.g.A[n][ks1][mf1][jh1][0][0], 16, 0, 0);
  }
  asm volatile("s_waitcnt vmcnt(2)" ::: "memory");  // ring0 landed; ring1 flies
  __builtin_amdgcn_sched_barrier(0);
  __builtin_amdgcn_s_barrier();
  __builtin_amdgcn_sched_barrier(0);

  // ---- 16 supersteps; ONE barrier each; no other manual waits needed:
  // gll(n+2) is older than B(n+1), so the compiler's B-register wait before
  // MFMA(n+1) retires gll(n+2) before barrier(n+1) -> ring visible at n+2.
  for (int n = 0; n < NSS; ++n) {
    const int ring = n % 3;
    // (1) B(n): 8 dwordx4 into regs (wave-private; flight under ds_read+cvt)
    f16x8 b[2][4];
    #pragma unroll
    for (int nf = 0; nf < 2; ++nf)
      #pragma unroll
      for (int ks = 0; ks < 4; ++ks)
        b[nf][ks] = *reinterpret_cast<const f16x8*>(
            wfB + (size_t)(n * 4 + ks) * 8192 + nf * 512);
    // (2) A(n): 8 fragments from LDS ring, cvt f32->fp16 (RNE)
    f16x8 a[2][4];
    #pragma unroll
    for (int mf = 0; mf < 2; ++mf)
      #pragma unroll
      for (int ks = 0; ks < 4; ++ks) {
        float4 lo = *reinterpret_cast<const float4*>(&sm.g.A[ring][ks][mf][0][lane][0]);
        float4 hi = *reinterpret_cast<const float4*>(&sm.g.A[ring][ks][mf][1][lane][0]);
        a[mf][ks] = cvt8(lo, hi);
      }
    __builtin_amdgcn_sched_barrier(0);
    // (3) stage A(n+2) into ring (n+2)%3 (reads of ring n are already issued)
    if (n + 2 < NSS) {
      const int r2 = (n + 2) % 3;
      __builtin_amdgcn_global_load_lds((g_float*)(s0 + (n + 2) * 128),
          (l_float*)&sm.g.A[r2][ks0][mf0][jh0][0][0], 16, 0, 0);
      __builtin_amdgcn_global_load_lds((g_float*)(s1 + (n + 2) * 128),
          (l_float*)&sm.g.A[r2][ks1][mf1][jh1][0][0], 16, 0, 0);
    }
    __builtin_amdgcn_sched_barrier(0);
    // (4) 16 MFMA
    #pragma unroll
    for (int ks = 0; ks < 4; ++ks) {
      acc[0][0] = __builtin_amdgcn_mfma_f32_16x16x32_f16(a[0][ks], b[0][ks], acc[0][0], 0, 0, 0);
      acc[1][0] = __builtin_amdgcn_mfma_f32_16x16x32_f16(a[1][ks], b[0][ks], acc[1][0], 0, 0, 0);
      acc[0][1] = __builtin_amdgcn_mfma_f32_16x16x32_f16(a[0][ks], b[1][ks], acc[0][1], 0, 0, 0);
      acc[1][1] = __builtin_amdgcn_mfma_f32_16x16x32_f16(a[1][ks], b[1][ks], acc[1][1], 0, 0, 0);
    }
    // (5) barrier: A(n+1) ring becomes safe to read next iter
    __builtin_amdgcn_sched_barrier(0);
    __builtin_amdgcn_s_barrier();
    __builtin_amdgcn_sched_barrier(0);
  }
  __syncthreads();   // full drain; safe to alias Sc over A

  // ---- epilogue: logits -> Sc (C/D layout: col=lane&15, row=(lane>>4)*4+r)
  #pragma unroll
  for (int mf = 0; mf < 2; ++mf)
    #pragma unroll
    for (int nf = 0; nf < 2; ++nf)
      #pragma unroll
      for (int r = 0; r < 4; ++r) {
        const int row = mf * 16 + ((lane >> 4) << 2) + r;
        const int col = wid * 32 + nf * 16 + (lane & 15);
        sm.Sc[row][col] = acc[mf][nf][r];
      }
  __syncthreads();

  // ---- routing: one wave per token, lane holds experts 4l..4l+3
  const float4 bsl = *reinterpret_cast<const float4*>(&bias[lane * 4]);
  const int g = lane >> 3;   // group of this lane's experts

  for (int m = wid; m < BM; m += 8) {
    float v[4];
    *reinterpret_cast<float4*>(v) =
        *reinterpret_cast<const float4*>(&sm.Sc[m][lane * 4]);

    // softmax (match jax: subtract row max, exp, divide by sum)
    float mx = fmaxf(fmaxf(v[0], v[1]), fmaxf(v[2], v[3]));
    #pragma unroll
    for (int s = 1; s < 64; s <<= 1) mx = fmaxf(mx, __shfl_xor(mx, s));
    float ex[4], sum = 0.f;
    #pragma unroll
    for (int j = 0; j < 4; ++j) { ex[j] = expf(v[j] - mx); sum += ex[j]; }
    #pragma unroll
    for (int s = 1; s < 64; s <<= 1) sum += __shfl_xor(sum, s);
    float sc[4], sel[4];
    sc[0] = ex[0] / sum; sc[1] = ex[1] / sum;
    sc[2] = ex[2] / sum; sc[3] = ex[3] / sum;
    sel[0] = sc[0] + bsl.x; sel[1] = sc[1] + bsl.y;
    sel[2] = sc[2] + bsl.z; sel[3] = sc[3] + bsl.w;

    // keep original scores for the gather
    *reinterpret_cast<float4*>(&sm.Sc[m][lane * 4]) =
        make_float4(sc[0], sc[1], sc[2], sc[3]);

    // group max (groups of 32 experts = 8 lanes)
    float gv = fmaxf(fmaxf(sel[0], sel[1]), fmaxf(sel[2], sel[3]));
    gv = fmaxf(gv, __shfl_xor(gv, 1));
    gv = fmaxf(gv, __shfl_xor(gv, 2));
    gv = fmaxf(gv, __shfl_xor(gv, 4));

    // top-4 groups, tie -> lower group index (jax.lax.top_k stability)
    unsigned gmask = 0;
    float gcur = gv;
    #pragma unroll
    for (int it = 0; it < NLIM; ++it) {
      float bv2 = gcur; int bi = g;
      #pragma unroll
      for (int s = 1; s < 64; s <<= 1) {
        float ov = __shfl_xor(bv2, s);
        int   oi = __shfl_xor(bi, s);
        if (ov > bv2 || (ov == bv2 && oi < bi)) { bv2 = ov; bi = oi; }
      }
      gmask |= 1u << bi;
      if (g == bi) gcur = -INFINITY;
    }
    if (!((gmask >> g) & 1u)) {
      sel[0] = sel[1] = sel[2] = sel[3] = -INFINITY;
    }

    // top-8 experts, tie -> lower expert index
    const int gtok = row0 + m;
    #pragma unroll
    for (int it = 0; it < TOPK; ++it) {
      float bv2 = sel[0]; int bi = lane * 4;
      #pragma unroll
      for (int j = 1; j < 4; ++j)
        if (sel[j] > bv2) { bv2 = sel[j]; bi = lane * 4 + j; }
      #pragma unroll
      for (int s = 1; s < 64; s <<= 1) {
        float ov = __shfl_xor(bv2, s);
        int   oi = __shfl_xor(bi, s);
        if (ov > bv2 || (ov == bv2 && oi < bi)) { bv2 = ov; bi = oi; }
      }
      if (lane == 0) {
        out_w[(size_t)gtok * TOPK + it]   = sm.Sc[m][bi] * 2.5f;
        out_idx[(size_t)gtok * TOPK + it] = (float)bi;
        atomicAdd(&hist[bi], 1);
      }
      if ((bi >> 2) == lane) sel[bi & 3] = -INFINITY;
    }
  }

  __syncthreads();
  for (int b = tid; b < NEXP; b += NTHREADS)
    if (hist[b]) atomicAdd(&out_load[b], (float)hist[b]);
}

extern "C" void kernel_launch(void* const* d_in, const int* in_sizes, int n_in,
                              void* d_out, int out_size, void* d_ws, size_t ws_size,
                              hipStream_t stream) {
  const float* x    = (const float*)d_in[0];
  const float* w    = (const float*)d_in[1];
  const float* bias = (const float*)d_in[2];
  float* out_w    = (float*)d_out;
  float* out_idx  = out_w + (size_t)T_TOKENS * TOPK;
  float* out_load = out_idx + (size_t)T_TOKENS * TOPK;
  unsigned short* wfrag = (unsigned short*)d_ws;   // 1 MB fragment-ordered fp16 w

  hipMemsetAsync(out_load, 0, NEXP * sizeof(float), stream);
  prep_w<<<256, 256, 0, stream>>>(w, wfrag);
  gate_kernel<<<T_TOKENS / BM, NTHREADS, 0, stream>>>(
      x, wfrag, bias, out_w, out_idx, out_load);
}